// Round 4
// baseline (44.862 us; speedup 1.0000x reference)
//
#include <hip/hip_runtime.h>
#include <math.h>

constexpr int B = 16, C = 3, H = 512, W = 384, N = 18;
constexpr int HW = H * W;

using v4f = __attribute__((ext_vector_type(4))) float;

// Cross-kernel param buffer in OUR module's device memory (not d_ws):
// per batch (72 floats, planar): [0..17] dst.x [18..35] dst.y
//                                [36..53] .5ln2*nodes.x [54..71] .5ln2*nodes.y
__device__ float g_params[B * 72];

// ---------------- threefry2x32 (JAX-compatible, key = (0,1)) ----------------
__device__ __forceinline__ unsigned rotl32(unsigned x, int d) {
    return (x << d) | (x >> (32 - d));
}

__device__ void threefry2x32_01(unsigned c0, unsigned c1, unsigned& o0, unsigned& o1) {
    const unsigned ks0 = 0u, ks1 = 1u, ks2 = 0x1BD11BDBu;  // 0 ^ 1 ^ 0x1BD11BDA
    unsigned x0 = c0 + ks0;
    unsigned x1 = c1 + ks1;
#define R4(a,b,c,d)                               \
    x0 += x1; x1 = rotl32(x1,(a)); x1 ^= x0;      \
    x0 += x1; x1 = rotl32(x1,(b)); x1 ^= x0;      \
    x0 += x1; x1 = rotl32(x1,(c)); x1 ^= x0;      \
    x0 += x1; x1 = rotl32(x1,(d)); x1 ^= x0;
    R4(13,15,26,6)   x0 += ks1; x1 += ks2 + 1u;
    R4(17,29,16,24)  x0 += ks2; x1 += ks0 + 2u;
    R4(13,15,26,6)   x0 += ks0; x1 += ks1 + 3u;
    R4(17,29,16,24)  x0 += ks1; x1 += ks2 + 4u;
    R4(13,15,26,6)   x0 += ks2; x1 += ks0 + 5u;
#undef R4
    o0 = x0; o1 = x1;
}

// -------- per-batch: jitter, build A (f64), register Gauss-Jordan ----------
__global__ __launch_bounds__(64) void solve_kernel(
        const float* __restrict__ keypoints,      // (B,N,2)
        const float* __restrict__ control_points) // (N,2)
{
    const int b = blockIdx.x;
    const int tid = threadIdx.x;
    __shared__ float dstx[N], dsty[N];
    __shared__ double Ab[N][20];   // cols 0..17 = A, 18..19 = rhs

    if (tid < 2 * N) {
        const int e = b * 2 * N + tid;  // element index in (16,18,2)
        const unsigned lo = (e < 288) ? (unsigned)e : (unsigned)(e - 288);
        unsigned o0, o1;
        threefry2x32_01(lo, lo + 288u, o0, o1);
        const unsigned bits = (e < 288) ? o0 : o1;
        const float f = __uint_as_float(0x3F800000u | (bits >> 9)) - 1.0f;
        const float lof = __uint_as_float(0xBF7FFFFFu);        // -0.99999994
        const float span = __uint_as_float(0x3FFFFFFFu);       //  1.99999994
        float u = f * span + lof;
        u = fmaxf(u, lof);
        const float nrm = 1.41421356f * erfinvf(u);            // sqrt(2) f32
        const float v = keypoints[e] + 1e-5f * nrm;
        if ((tid & 1) == 0) dstx[tid >> 1] = v; else dsty[tid >> 1] = v;
    }
    __syncthreads();

    // Build [A | rhs] in f64, spread across all 64 lanes (parallel f64 logs)
    for (int idx = tid; idx < N * 20; idx += 64) {
        const int i = idx / 20, j = idx - (idx / 20) * 20;
        double v;
        if (j < N) {
            const double dx = (double)dstx[i] - (double)dstx[j];
            const double dy = (double)dsty[i] - (double)dsty[j];
            const double d2 = dx * dx + dy * dy;
            const double phi = (d2 > 0.0) ? 0.5 * d2 * log(d2) : 0.0;
            v = phi - (i == j ? 1e-5 : 0.0);
        } else {
            v = (double)control_points[2 * i + (j - N)];
        }
        Ab[i][j] = v;
    }
    __syncthreads();

    // Each lane owns one row in registers (lanes >= 18 mirror row 17, inert)
    const int row = min(tid, N - 1);
    double a[20];
#pragma unroll
    for (int j = 0; j < 20; ++j) a[j] = Ab[row][j];

    bool used = (tid >= N);
    double invs = 0.0;
    int myvar = -1;

#pragma unroll
    for (int k = 0; k < N; ++k) {
        // wave argmax of |a[k]| over unused rows (first-max tie-break)
        double cand = used ? -1.0 : fabs(a[k]);
        int il = tid;
#pragma unroll
        for (int off = 32; off >= 1; off >>= 1) {
            const double oc = __shfl_xor(cand, off);
            const int oi = __shfl_xor(il, off);
            if (oc > cand || (oc == cand && oi < il)) { cand = oc; il = oi; }
        }
        const int p = __shfl(il, 0);
        const double piv = __shfl(a[k], p);
        const double inv = 1.0 / piv;
        const bool iam = (tid == p);
        if (iam) { used = true; myvar = k; invs = inv; }
        const double m = iam ? 0.0 : a[k] * inv;
        // eliminate column k, j in (k..17] + rhs (earlier pivoted cols inert)
#pragma unroll
        for (int j = k + 1; j < 20; ++j) {
            const double prj = __shfl(a[j], p);
            a[j] = fma(-m, prj, a[j]);
        }
    }

    float* pb = g_params + b * 72;
    if (tid < N) { pb[tid] = dstx[tid]; pb[18 + tid] = dsty[tid]; }
    if (myvar >= 0) {
        const double sc = 0.34657359027997264;  // 0.5 * ln(2): warp uses log2
        pb[36 + myvar] = (float)(sc * a[18] * invs);
        pb[54 + myvar] = (float)(sc * a[19] * invs);
    }
}

// ---------------- per-pixel TPS evaluation + bilinear sample ----------------
// 4 horizontally-adjacent pixels per thread; XCD-chunked block swizzle
__global__ __launch_bounds__(256) void warp_kernel(
        const float* __restrict__ image,   // (B,C,H,W)
        float* __restrict__ out) {         // (B,C,H,W)
    constexpr int PPB = 1024;              // pixels per block
    constexpr int BPB = HW / PPB;          // 192 blocks per batch
    constexpr int NBLK = B * BPB;          // 3072 (divisible by 8 -> simple swz)
    const int bid = blockIdx.x;
    const int swz = (bid & 7) * (NBLK / 8) + (bid >> 3);
    const int b = swz / BPB;
    const int pix0 = (swz - b * BPB) * PPB + threadIdx.x * 4;
    const int y = pix0 / W;
    const int x = pix0 - y * W;            // W%4==0: 4 px never straddle rows

    const float* __restrict__ pb = g_params + b * 72; // block-uniform -> s_load
    const float py = (float)y;
    const v4f px = { (float)x, (float)(x + 1), (float)(x + 2), (float)(x + 3) };
    v4f ax = { 0.f, 0.f, 0.f, 0.f }, ay = { 0.f, 0.f, 0.f, 0.f };
#pragma unroll
    for (int n = 0; n < N; ++n) {
        const float kx = pb[n];
        const float ky = pb[18 + n];
        const float nx = pb[36 + n];       // pre-scaled by 0.5*ln2
        const float ny = pb[54 + n];
        const float dy = py - ky;
        const float dy2 = dy * dy;
        const v4f dx = px - kx;
        v4f r2 = dx * dx + dy2;
        v4f lg;
#pragma unroll
        for (int j = 0; j < 4; ++j) {
            r2[j] = fmaxf(r2[j], 1e-30f);  // r2==0 -> phi ~ -1e-28 ~= 0
            lg[j] = __builtin_amdgcn_logf(r2[j]);  // native v_log_f32 (log2)
        }
        const v4f phi = r2 * lg;
        ax += phi * nx;
        ay += phi * ny;
    }

    const float* imb = image + (size_t)b * C * HW;
    float* outb = out + (size_t)b * C * HW;
    v4f o0, o1, o2;
#pragma unroll
    for (int j = 0; j < 4; ++j) {
        const float wx = fminf(fmaxf(ax[j], 0.f), (float)(W - 1));
        const float wy = fminf(fmaxf(ay[j], 0.f), (float)(H - 1));
        const float xf = floorf(wx), yf = floorf(wy);
        const int x0 = min(max((int)xf, 0), W - 1);
        const int x1 = min(max((int)(xf + 1.f), 0), W - 1);
        const int y0 = min(max((int)yf, 0), H - 1);
        const int y1 = min(max((int)(yf + 1.f), 0), H - 1);
        // weights use CLIPPED integer corners (reference semantics)
        const float wa = ((float)x1 - wx) * ((float)y1 - wy);
        const float wb = ((float)x1 - wx) * (wy - (float)y0);
        const float wc = (wx - (float)x0) * ((float)y1 - wy);
        const float wd = (wx - (float)x0) * (wy - (float)y0);
        const int ia = y0 * W + x0, ib = y1 * W + x0;
        const int ic = y0 * W + x1, id = y1 * W + x1;
        o0[j] = wa * imb[ia] + wb * imb[ib] + wc * imb[ic] + wd * imb[id];
        const float* c1 = imb + HW;
        o1[j] = wa * c1[ia] + wb * c1[ib] + wc * c1[ic] + wd * c1[id];
        const float* c2 = imb + 2 * HW;
        o2[j] = wa * c2[ia] + wb * c2[ib] + wc * c2[ic] + wd * c2[id];
    }
    *reinterpret_cast<v4f*>(outb + pix0) = o0;
    *reinterpret_cast<v4f*>(outb + HW + pix0) = o1;
    *reinterpret_cast<v4f*>(outb + 2 * HW + pix0) = o2;
}

extern "C" void kernel_launch(void* const* d_in, const int* in_sizes, int n_in,
                              void* d_out, int out_size, void* d_ws, size_t ws_size,
                              hipStream_t stream) {
    const float* cloth     = (const float*)d_in[0];
    const float* keypoints = (const float*)d_in[1];
    const float* ctrl      = (const float*)d_in[2];
    (void)d_ws; (void)ws_size;  // deliberately unused: A/B test on harness ws re-poison

    solve_kernel<<<B, 64, 0, stream>>>(keypoints, ctrl);
    warp_kernel<<<(B * HW) / 1024, 256, 0, stream>>>(cloth, (float*)d_out);
}

// Round 5
// 40.740 us; speedup vs baseline: 1.1012x; 1.1012x over previous
//
#include <hip/hip_runtime.h>
#include <math.h>

constexpr int B = 16, C = 3, H = 512, W = 384, N = 18;
constexpr int HW = H * W;

using v4f = __attribute__((ext_vector_type(4))) float;

// Cross-kernel param buffer in OUR module's device memory:
// per batch (72 floats, planar): [0..17] dst.x [18..35] dst.y
//                                [36..53] .5ln2*nodes.x [54..71] .5ln2*nodes.y
__device__ float g_params[B * 72];

// ---------------- threefry2x32 (JAX-compatible, key = (0,1)) ----------------
__device__ __forceinline__ unsigned rotl32(unsigned x, int d) {
    return (x << d) | (x >> (32 - d));
}

__device__ void threefry2x32_01(unsigned c0, unsigned c1, unsigned& o0, unsigned& o1) {
    const unsigned ks0 = 0u, ks1 = 1u, ks2 = 0x1BD11BDBu;  // 0 ^ 1 ^ 0x1BD11BDA
    unsigned x0 = c0 + ks0;
    unsigned x1 = c1 + ks1;
#define R4(a,b,c,d)                               \
    x0 += x1; x1 = rotl32(x1,(a)); x1 ^= x0;      \
    x0 += x1; x1 = rotl32(x1,(b)); x1 ^= x0;      \
    x0 += x1; x1 = rotl32(x1,(c)); x1 ^= x0;      \
    x0 += x1; x1 = rotl32(x1,(d)); x1 ^= x0;
    R4(13,15,26,6)   x0 += ks1; x1 += ks2 + 1u;
    R4(17,29,16,24)  x0 += ks2; x1 += ks0 + 2u;
    R4(13,15,26,6)   x0 += ks0; x1 += ks1 + 3u;
    R4(17,29,16,24)  x0 += ks1; x1 += ks2 + 4u;
    R4(13,15,26,6)   x0 += ks2; x1 += ks0 + 5u;
#undef R4
    o0 = x0; o1 = x1;
}

// -------- per-batch: jitter, build A (f64), register Gauss-Jordan ----------
__global__ __launch_bounds__(64) void solve_kernel(
        const float* __restrict__ keypoints,      // (B,N,2)
        const float* __restrict__ control_points) // (N,2)
{
    const int b = blockIdx.x;
    const int tid = threadIdx.x;
    __shared__ float dstx[N], dsty[N];
    __shared__ double Ab[N][20];   // cols 0..17 = A, 18..19 = rhs

    if (tid < 2 * N) {
        const int e = b * 2 * N + tid;  // element index in (16,18,2)
        const unsigned lo = (e < 288) ? (unsigned)e : (unsigned)(e - 288);
        unsigned o0, o1;
        threefry2x32_01(lo, lo + 288u, o0, o1);
        const unsigned bits = (e < 288) ? o0 : o1;
        const float f = __uint_as_float(0x3F800000u | (bits >> 9)) - 1.0f;
        const float lof = __uint_as_float(0xBF7FFFFFu);        // -0.99999994
        const float span = __uint_as_float(0x3FFFFFFFu);       //  1.99999994
        float u = f * span + lof;
        u = fmaxf(u, lof);
        const float nrm = 1.41421356f * erfinvf(u);            // sqrt(2) f32
        const float v = keypoints[e] + 1e-5f * nrm;
        if ((tid & 1) == 0) dstx[tid >> 1] = v; else dsty[tid >> 1] = v;
    }
    __syncthreads();

    // Build [A | rhs] in f64, spread across all 64 lanes (parallel f64 logs)
    for (int idx = tid; idx < N * 20; idx += 64) {
        const int i = idx / 20, j = idx - (idx / 20) * 20;
        double v;
        if (j < N) {
            const double dx = (double)dstx[i] - (double)dstx[j];
            const double dy = (double)dsty[i] - (double)dsty[j];
            const double d2f = fmax(dx * dx + dy * dy, 1e-300);
            // d2==0 only on diagonal: 0.5*d2*log(d2f) -> exactly 0 there
            const double phi = 0.5 * (dx * dx + dy * dy) * log(d2f);
            v = phi - (i == j ? 1e-5 : 0.0);
        } else {
            v = (double)control_points[2 * i + (j - N)];
        }
        Ab[i][j] = v;
    }
    __syncthreads();

    // Each lane owns one row in registers (lanes >= 18 mirror row 17, inert)
    const int row = min(tid, N - 1);
    double a[20];
#pragma unroll
    for (int j = 0; j < 20; ++j) a[j] = Ab[row][j];

    bool used = (tid >= N);
    double invs = 0.0;
    int myvar = -1;

#pragma unroll
    for (int k = 0; k < N; ++k) {
        // packed-key wave argmax over unused rows (lanes 0..31 relevant):
        // key = hi-word of |a[k]| with low 6 bits = (63 - lane)  ->
        // u32 ordering == truncated-magnitude ordering, lane tiebreak baked in
        const unsigned hi =
            (unsigned)((unsigned long long)__double_as_longlong(a[k]) >> 32)
            & 0x7FFFFFFFu;
        unsigned key = used ? 0u : ((hi & ~63u) | (63u - (unsigned)tid));
#pragma unroll
        for (int off = 16; off >= 1; off >>= 1) {
            const unsigned ok = __shfl_xor(key, off);
            key = key > ok ? key : ok;
        }
        const int p = __shfl(63 - (int)(key & 63u), 0);  // uniform, from lane 0
        const double piv = __shfl(a[k], p);
        const double inv = 1.0 / piv;
        const bool iam = (tid == p) && (tid < N);
        if (iam) { used = true; myvar = k; invs = inv; }
        const double m = iam ? 0.0 : a[k] * inv;
        // eliminate column k, j in (k..17] + rhs (earlier pivoted cols inert)
#pragma unroll
        for (int j = k + 1; j < 20; ++j) {
            const double prj = __shfl(a[j], p);
            a[j] = fma(-m, prj, a[j]);
        }
    }

    float* pb = g_params + b * 72;
    if (tid < N) { pb[tid] = dstx[tid]; pb[18 + tid] = dsty[tid]; }
    if (myvar >= 0) {
        const double sc = 0.34657359027997264;  // 0.5 * ln(2): warp uses log2
        pb[36 + myvar] = (float)(sc * a[18] * invs);
        pb[54 + myvar] = (float)(sc * a[19] * invs);
    }
}

// ---------------- per-pixel TPS evaluation + bilinear sample ----------------
// 4 horizontally-adjacent pixels per thread; XCD-chunked block swizzle
__global__ __launch_bounds__(256) void warp_kernel(
        const float* __restrict__ image,   // (B,C,H,W)
        float* __restrict__ out) {         // (B,C,H,W)
    constexpr int PPB = 1024;              // pixels per block
    constexpr int BPB = HW / PPB;          // 192 blocks per batch
    constexpr int NBLK = B * BPB;          // 3072 (divisible by 8 -> simple swz)
    const int bid = blockIdx.x;
    const int swz = (bid & 7) * (NBLK / 8) + (bid >> 3);
    const int b = swz / BPB;
    const int pix0 = (swz - b * BPB) * PPB + threadIdx.x * 4;
    const int y = pix0 / W;
    const int x = pix0 - y * W;            // W%4==0: 4 px never straddle rows

    const float* __restrict__ pb = g_params + b * 72; // block-uniform -> s_load
    const float py = (float)y;
    const v4f px = { (float)x, (float)(x + 1), (float)(x + 2), (float)(x + 3) };
    v4f ax = { 0.f, 0.f, 0.f, 0.f }, ay = { 0.f, 0.f, 0.f, 0.f };
#pragma unroll
    for (int n = 0; n < N; ++n) {
        const float kx = pb[n];
        const float ky = pb[18 + n];
        const float nx = pb[36 + n];       // pre-scaled by 0.5*ln2
        const float ny = pb[54 + n];
        const float dy = py - ky;
        const float dy2 = dy * dy;
        const v4f dx = px - kx;
        v4f r2 = dx * dx + dy2;
        v4f lg;
#pragma unroll
        for (int j = 0; j < 4; ++j) {
            r2[j] = fmaxf(r2[j], 1e-30f);  // r2==0 -> phi ~ -1e-28 ~= 0
            lg[j] = __builtin_amdgcn_logf(r2[j]);  // native v_log_f32 (log2)
        }
        const v4f phi = r2 * lg;
        ax += phi * nx;
        ay += phi * ny;
    }

    const float* imb = image + (size_t)b * C * HW;
    float* outb = out + (size_t)b * C * HW;
    v4f o0, o1, o2;
#pragma unroll
    for (int j = 0; j < 4; ++j) {
        const float wx = fminf(fmaxf(ax[j], 0.f), (float)(W - 1));
        const float wy = fminf(fmaxf(ay[j], 0.f), (float)(H - 1));
        const float xf = floorf(wx), yf = floorf(wy);
        // wx in [0, W-1] already => x0 = (int)xf needs no clamp; x1 one min.
        const int x0 = (int)xf;
        const int x1 = min(x0 + 1, W - 1);
        const int y0 = (int)yf;
        const int y1 = min(y0 + 1, H - 1);
        // weights use CLIPPED integer corners (reference semantics)
        const float wa = ((float)x1 - wx) * ((float)y1 - wy);
        const float wb = ((float)x1 - wx) * (wy - (float)y0);
        const float wc = (wx - (float)x0) * ((float)y1 - wy);
        const float wd = (wx - (float)x0) * (wy - (float)y0);
        const int ia = y0 * W + x0, ib = y1 * W + x0;
        const int ic = y0 * W + x1, id = y1 * W + x1;
        o0[j] = wa * imb[ia] + wb * imb[ib] + wc * imb[ic] + wd * imb[id];
        const float* c1 = imb + HW;
        o1[j] = wa * c1[ia] + wb * c1[ib] + wc * c1[ic] + wd * c1[id];
        const float* c2 = imb + 2 * HW;
        o2[j] = wa * c2[ia] + wb * c2[ib] + wc * c2[ic] + wd * c2[id];
    }
    *reinterpret_cast<v4f*>(outb + pix0) = o0;
    *reinterpret_cast<v4f*>(outb + HW + pix0) = o1;
    *reinterpret_cast<v4f*>(outb + 2 * HW + pix0) = o2;
}

extern "C" void kernel_launch(void* const* d_in, const int* in_sizes, int n_in,
                              void* d_out, int out_size, void* d_ws, size_t ws_size,
                              hipStream_t stream) {
    const float* cloth     = (const float*)d_in[0];
    const float* keypoints = (const float*)d_in[1];
    const float* ctrl      = (const float*)d_in[2];
    (void)d_ws; (void)ws_size;

    solve_kernel<<<B, 64, 0, stream>>>(keypoints, ctrl);
    warp_kernel<<<(B * HW) / 1024, 256, 0, stream>>>(cloth, (float*)d_out);
}